// Round 26
// baseline (814.061 us; speedup 1.0000x reference)
//
#include <hip/hip_runtime.h>
#include <hip/hip_bf16.h>
#include <stdint.h>

typedef float f32x4 __attribute__((ext_vector_type(4)));
typedef float f32x16 __attribute__((ext_vector_type(16)));
typedef int i32x4 __attribute__((ext_vector_type(4)));
typedef int i32x8 __attribute__((ext_vector_type(8)));
typedef long i64;

#define BM 256
#define BN 128
#define BKB 64   // K elements (=bytes, fp8) per tile step

// 16B-chunk slot = chunk ^ swz(row); period 16 covers the 32-row frag read.
__device__ __host__ __forceinline__ int swz(int r) {
  return ((r >> 1) ^ (r >> 3)) & 3;
}

// ---------------- pre-quant: fp32 (bf16-valued) -> fp8 e4m3fn, LINEAR -------
__global__ __launch_bounds__(256) void quant_fp8_from_f32(
    const float* __restrict__ in, const float* __restrict__ scale,
    uint8_t* __restrict__ out, int n16) {
  const int i = blockIdx.x * blockDim.x + threadIdx.x;
  if (i >= n16) return;
  const float inv_s = 1.0f / scale[0];
  const float* p = in + (i64)i * 16;
  f32x4 v[4];
  v[0] = *(const f32x4*)p;
  v[1] = *(const f32x4*)(p + 4);
  v[2] = *(const f32x4*)(p + 8);
  v[3] = *(const f32x4*)(p + 12);
  uint32_t w[4];
#pragma unroll
  for (int q = 0; q < 4; q++) {
    float f0 = fminf(fmaxf(v[q][0] * inv_s, -448.f), 448.f);
    float f1 = fminf(fmaxf(v[q][1] * inv_s, -448.f), 448.f);
    float f2 = fminf(fmaxf(v[q][2] * inv_s, -448.f), 448.f);
    float f3 = fminf(fmaxf(v[q][3] * inv_s, -448.f), 448.f);
    int r = 0;
    r = __builtin_amdgcn_cvt_pk_fp8_f32(f0, f1, r, false);
    r = __builtin_amdgcn_cvt_pk_fp8_f32(f2, f3, r, true);
    w[q] = (uint32_t)r;
  }
  ((uint4*)out)[i] = make_uint4(w[0], w[1], w[2], w[3]);
}

__device__ __forceinline__ void gload_lds16(const void* g, void* l) {
  __builtin_amdgcn_global_load_lds(
      (const __attribute__((address_space(1))) uint32_t*)g,
      (__attribute__((address_space(3))) uint32_t*)l, 16, 0, 0);
}

__device__ __forceinline__ float bf16_rne_f32(float f) {
  union { float f; uint32_t u; } c; c.f = f;
  uint32_t lsb = (c.u >> 16) & 1u;
  c.u += 0x7FFFu + lsb;
  c.u &= 0xFFFF0000u;
  return c.f;
}

// ---------------- fp8 GEMM via MX-scaled 32x32x64 MFMA (scales = 1.0) -------
// 256x128 tile, 4 waves (2Mx2N), wave-tile 128x64, acc[4][2] f32x16 (128 reg).
// A staged in LDS (dbuf 2x16KB, swizzled gload_lds); B read DIRECT from
// global into registers (lane l row = wn+j*32+(l&31), k = it*64+(l>>5)*32:
// lane pairs (l,l+32) cover one full 64B line -> perfect L2 line use).
// Cuts LDS traffic 96->64 KB/block-step (the R23/R25-measured LDS-BW wall).
// B double-buffered in regs (ubA/ubB static names, 2-step unrolled loop);
// issue order per step = [4 A-stage gload_lds, 4 B global loads] so
// vmcnt(8) drains exactly the PREVIOUS step's 8 ops (per-thread FIFO, R18).
// 2 blocks/CU (LDS 32KB, regs ~243 <= 256 at 2 waves/SIMD).
__global__ __launch_bounds__(256, 2) void gemm_fp8_mx(
    const uint8_t* __restrict__ Aq, const uint8_t* __restrict__ Bq,
    const float* __restrict__ bias,
    const float* __restrict__ xs, const float* __restrict__ wsc,
    float* __restrict__ C, int M, int N, int K) {
  __shared__ uint8_t sA[2][BM * BKB];   // 2 x 16 KB (A only)

  const int nbn = N / BN;
  int bid = blockIdx.x;
  { int cpx = gridDim.x >> 3; bid = (bid & 7) * cpx + (bid >> 3); }  // XCD swizzle
  const int bm = bid / nbn;
  const int bn = bid % nbn;

  const int t = threadIdx.x, lane = t & 63, wave = t >> 6;
  const int wm = (wave >> 1) * 128;   // 2 wave-rows of 128
  const int wn = (wave & 1) * 64;     // 2 wave-cols of 64
  const int g = lane >> 5;            // K-half group
  const int r31 = lane & 31;

  f32x16 acc[4][2];
#pragma unroll
  for (int i = 0; i < 4; i++)
#pragma unroll
    for (int j = 0; j < 2; j++) acc[i][j] = (f32x16)0.f;

  // ---- A staging: thread t stages chunk (t&3) of rows (t>>2)+64j, j=0..3 ----
  const int srow = t >> 2;            // 0..63
  const int c16 = t & 3;
  i64 src[4];
#pragma unroll
  for (int j = 0; j < 4; j++) {
    const int row = srow + 64 * j;
    src[j] = (i64)row * K + ((c16 ^ swz(row)) << 4);
  }
  const uint8_t* gA = Aq + (i64)(bm * BM) * K;

  // ---- B direct-load bases (per lane): row = bn*BN + wn + j*32 + r31 ----
  const uint8_t* bbase[2];
#pragma unroll
  for (int j = 0; j < 2; j++)
    bbase[j] = Bq + (i64)(bn * BN + wn + j * 32 + r31) * K + g * 32;

  // ---- A fragment read offsets (hoisted) ----
  int aoff[4][2];
#pragma unroll
  for (int i = 0; i < 4; i++) {
    const int ra = wm + i * 32 + r31;
    const int sa_ = swz(ra);
    aoff[i][0] = ra * 64 + (((2 * g + 0) ^ sa_) << 4);
    aoff[i][1] = ra * 64 + (((2 * g + 1) ^ sa_) << 4);
  }

  const int NT = K / BKB;
  union opnd { i32x4 h[2]; i32x8 v; };
  opnd ubA[2], ubB[2];

  // prologue: stage A tile0 (4 gloads), load B step0 (4 loads) -- FIFO order
#pragma unroll
  for (int j = 0; j < 4; j++)
    gload_lds16(gA + src[j], &sA[0][t * 16 + j * 4096]);
#pragma unroll
  for (int j = 0; j < 2; j++) {
    ubA[j].h[0] = *(const i32x4*)(bbase[j] + 0);
    ubA[j].h[1] = *(const i32x4*)(bbase[j] + 16);
  }

#define STEP(PARITY, UBC, UBN, ITV)                                          \
  {                                                                          \
    const int itv = (ITV);                                                   \
    if (itv + 1 < NT) {                                                      \
      const i64 kt = (i64)(itv + 1) * BKB;                                   \
      _Pragma("unroll")                                                      \
      for (int j = 0; j < 4; j++)                                            \
        gload_lds16(gA + src[j] + kt, &sA[PARITY ^ 1][t * 16 + j * 4096]);   \
      _Pragma("unroll")                                                      \
      for (int j = 0; j < 2; j++) {                                          \
        UBN[j].h[0] = *(const i32x4*)(bbase[j] + kt);                        \
        UBN[j].h[1] = *(const i32x4*)(bbase[j] + kt + 16);                   \
      }                                                                      \
      asm volatile("s_waitcnt vmcnt(8)" ::: "memory");                       \
    } else {                                                                 \
      asm volatile("s_waitcnt vmcnt(0)" ::: "memory");                       \
    }                                                                        \
    __builtin_amdgcn_s_barrier();                                            \
    _Pragma("unroll")                                                        \
    for (int i = 0; i < 4; i++) {                                            \
      opnd ua;                                                               \
      ua.h[0] = *(const i32x4*)(&sA[PARITY][0] + aoff[i][0]);                \
      ua.h[1] = *(const i32x4*)(&sA[PARITY][0] + aoff[i][1]);                \
      _Pragma("unroll")                                                      \
      for (int j = 0; j < 2; j++)                                            \
        acc[i][j] = __builtin_amdgcn_mfma_scale_f32_32x32x64_f8f6f4(         \
            ua.v, UBC[j].v, acc[i][j], 0, 0, 0, 127, 0, 127);                \
    }                                                                        \
    __builtin_amdgcn_s_barrier();                                            \
  }

  for (int it = 0; it < NT; it += 2) {
    STEP(0, ubA, ubB, it);
    STEP(1, ubB, ubA, it + 1);
  }
#undef STEP

  // ---- epilogue: bf16_rne(acc*(sx*sw) + bias) stored as FP32 -------------
  // 32x32 C/D layout (m74/m101): col = lane&31, row = (reg&3)+8*(reg>>2)+4*g
  const float sc = xs[0] * wsc[0];
#pragma unroll
  for (int j = 0; j < 2; j++) {
    const int col = bn * BN + wn + j * 32 + r31;
    const float bv = bias[col];
#pragma unroll
    for (int i = 0; i < 4; i++) {
      const int rowbase = bm * BM + wm + i * 32 + 4 * g;
#pragma unroll
      for (int reg = 0; reg < 16; reg++) {
        const int row = rowbase + (reg & 3) + 8 * (reg >> 2);
        C[(i64)row * N + col] = bf16_rne_f32(acc[i][j][reg] * sc + bv);
      }
    }
  }
}

extern "C" void kernel_launch(void* const* d_in, const int* in_sizes, int n_in,
                              void* d_out, int out_size, void* d_ws, size_t ws_size,
                              hipStream_t stream) {
  // Verified I/O model (R11 oracle + R12-R25 passes): declared order, element
  // counts, ALL buffers fp32-stored bf16-valued, output fp32.
  const float* x = (const float*)d_in[0];
  const float* w = (const float*)d_in[1];
  const float* bias = (const float*)d_in[2];
  const float* x_scale = (const float*)d_in[3];
  const float* w_scale = (const float*)d_in[4];

  const int N = in_sizes[2];
  const int K = in_sizes[1] / N;
  const int M = in_sizes[0] / K;

  uint8_t* xq = (uint8_t*)d_ws;                     // M*K = 32 MB
  uint8_t* wq = (uint8_t*)d_ws + (size_t)M * K;     // N*K = 64 MB

  {
    const int n16 = (M * K) / 16;
    quant_fp8_from_f32<<<(n16 + 255) / 256, 256, 0, stream>>>(x, x_scale, xq, n16);
  }
  {
    const int n16 = (int)(((i64)N * K) / 16);
    quant_fp8_from_f32<<<(n16 + 255) / 256, 256, 0, stream>>>(w, w_scale, wq, n16);
  }

  dim3 grid((M / BM) * (N / BN));
  gemm_fp8_mx<<<grid, 256, 0, stream>>>(
      xq, wq, bias, x_scale, w_scale, (float*)d_out, M, N, K);
}

// Round 27
// 725.660 us; speedup vs baseline: 1.1218x; 1.1218x over previous
//
#include <hip/hip_runtime.h>
#include <hip/hip_bf16.h>
#include <stdint.h>

typedef float f32x4 __attribute__((ext_vector_type(4)));
typedef float f32x16 __attribute__((ext_vector_type(16)));
typedef int i32x4 __attribute__((ext_vector_type(4)));
typedef int i32x8 __attribute__((ext_vector_type(8)));
typedef long i64;

#define BM 256
#define BN 128
#define BKB 64   // K elements (=bytes, fp8) per tile step

// 16B-chunk slot = chunk ^ swz(row); period 16 covers the 32-row frag read.
__device__ __host__ __forceinline__ int swz(int r) {
  return ((r >> 1) ^ (r >> 3)) & 3;
}

// ---------------- pre-quant: fp32 (bf16-valued) -> fp8 e4m3fn, LINEAR -------
__global__ __launch_bounds__(256) void quant_fp8_from_f32(
    const float* __restrict__ in, const float* __restrict__ scale,
    uint8_t* __restrict__ out, int n16) {
  const int i = blockIdx.x * blockDim.x + threadIdx.x;
  if (i >= n16) return;
  const float inv_s = 1.0f / scale[0];
  const float* p = in + (i64)i * 16;
  f32x4 v[4];
  v[0] = *(const f32x4*)p;
  v[1] = *(const f32x4*)(p + 4);
  v[2] = *(const f32x4*)(p + 8);
  v[3] = *(const f32x4*)(p + 12);
  uint32_t w[4];
#pragma unroll
  for (int q = 0; q < 4; q++) {
    float f0 = fminf(fmaxf(v[q][0] * inv_s, -448.f), 448.f);
    float f1 = fminf(fmaxf(v[q][1] * inv_s, -448.f), 448.f);
    float f2 = fminf(fmaxf(v[q][2] * inv_s, -448.f), 448.f);
    float f3 = fminf(fmaxf(v[q][3] * inv_s, -448.f), 448.f);
    int r = 0;
    r = __builtin_amdgcn_cvt_pk_fp8_f32(f0, f1, r, false);
    r = __builtin_amdgcn_cvt_pk_fp8_f32(f2, f3, r, true);
    w[q] = (uint32_t)r;
  }
  ((uint4*)out)[i] = make_uint4(w[0], w[1], w[2], w[3]);
}

__device__ __forceinline__ void gload_lds16(const void* g, void* l) {
  __builtin_amdgcn_global_load_lds(
      (const __attribute__((address_space(1))) uint32_t*)g,
      (__attribute__((address_space(3))) uint32_t*)l, 16, 0, 0);
}

__device__ __forceinline__ float bf16_rne_f32(float f) {
  union { float f; uint32_t u; } c; c.f = f;
  uint32_t lsb = (c.u >> 16) & 1u;
  c.u += 0x7FFFu + lsb;
  c.u &= 0xFFFF0000u;
  return c.f;
}

// ---------------- fp8 GEMM via MX-scaled 32x32x64 MFMA (scales = 1.0) -------
// 256x128 tile, 4 waves (2Mx2N), wave-tile 128x64, acc[4][2] f32x16 (128 reg)
// -- R25's exact data paths (A,B in LDS, swizzled gload_lds, counted vmcnt).
// NEW: TRIPLE-buffered LDS (3 x 24KB = 72KB -> 2 blocks/CU) with ONE barrier
// per K-step (R25 paid 2). Step t: vmcnt(6) [tile t landed; tile t+1 stays in
// flight, 2 steps of slack]; barrier; ds_read buf[t%3]; stage t+2 into
// buf[(t+2)%3] (issue hides under MFMA); setprio(1) MFMA setprio(0).
// Race audit: buf[(t+2)%3] was last read at step t-1, and ALL waves finished
// step t-1 reads before crossing step t's barrier (reads are data-bound
// before their MFMAs, MFMAs precede the barrier in program order).
__global__ __launch_bounds__(256, 2) void gemm_fp8_mx(
    const uint8_t* __restrict__ Aq, const uint8_t* __restrict__ Bq,
    const float* __restrict__ bias,
    const float* __restrict__ xs, const float* __restrict__ wsc,
    float* __restrict__ C, int M, int N, int K) {
  __shared__ uint8_t sA[3][BM * BKB];   // 3 x 16 KB
  __shared__ uint8_t sB[3][BN * BKB];   // 3 x 8 KB

  const int nbn = N / BN;
  int bid = blockIdx.x;
  { int cpx = gridDim.x >> 3; bid = (bid & 7) * cpx + (bid >> 3); }  // XCD swizzle
  const int bm = bid / nbn;
  const int bn = bid % nbn;

  const int t = threadIdx.x, lane = t & 63, wave = t >> 6;
  const int wm = (wave >> 1) * 128;   // 2 wave-rows of 128
  const int wn = (wave & 1) * 64;     // 2 wave-cols of 64
  const int g = lane >> 5;            // K-half group
  const int r31 = lane & 31;

  f32x16 acc[4][2];
#pragma unroll
  for (int i = 0; i < 4; i++)
#pragma unroll
    for (int j = 0; j < 2; j++) acc[i][j] = (f32x16)0.f;

  // ---- staging: thread t stages chunk (t&3) of rows (t>>2)+64j ----
  // A: j=0..3 (256 rows), B: j=0..1 (128 rows). 6 gloads/thread/step.
  const int srow = t >> 2;            // 0..63
  const int c16 = t & 3;
  i64 src[4];
#pragma unroll
  for (int j = 0; j < 4; j++) {
    const int row = srow + 64 * j;
    src[j] = (i64)row * K + ((c16 ^ swz(row)) << 4);
  }
  const uint8_t* gA = Aq + (i64)(bm * BM) * K;
  const uint8_t* gB = Bq + (i64)(bn * BN) * K;

  // ---- fragment read offsets (hoisted) ----
  int aoff[4][2], boff[2][2];
#pragma unroll
  for (int i = 0; i < 4; i++) {
    const int ra = wm + i * 32 + r31;
    const int sa_ = swz(ra);
    aoff[i][0] = ra * 64 + (((2 * g + 0) ^ sa_) << 4);
    aoff[i][1] = ra * 64 + (((2 * g + 1) ^ sa_) << 4);
  }
#pragma unroll
  for (int j = 0; j < 2; j++) {
    const int rb = wn + j * 32 + r31;
    const int sb_ = swz(rb);
    boff[j][0] = rb * 64 + (((2 * g + 0) ^ sb_) << 4);
    boff[j][1] = rb * 64 + (((2 * g + 1) ^ sb_) << 4);
  }

  const int NT = K / BKB;
  // prologue: stage tiles 0,1 into buffers 0,1 (12 loads/thread in flight)
#pragma unroll
  for (int j = 0; j < 4; j++) {
    gload_lds16(gA + src[j], &sA[0][t * 16 + j * 4096]);
  }
#pragma unroll
  for (int j = 0; j < 2; j++)
    gload_lds16(gB + src[j], &sB[0][t * 16 + j * 4096]);
#pragma unroll
  for (int j = 0; j < 4; j++)
    gload_lds16(gA + src[j] + BKB, &sA[1][t * 16 + j * 4096]);
#pragma unroll
  for (int j = 0; j < 2; j++)
    gload_lds16(gB + src[j] + BKB, &sB[1][t * 16 + j * 4096]);

  int cur = 0, st2 = 2;   // read buffer, stage buffer (= (it+2)%3)
  for (int it = 0; it < NT; ++it) {
    if (it + 1 < NT) {
      asm volatile("s_waitcnt vmcnt(6)" ::: "memory");   // tile `it` landed
    } else {
      asm volatile("s_waitcnt vmcnt(0)" ::: "memory");
    }
    __builtin_amdgcn_s_barrier();   // single barrier per step

    const uint8_t* bufA = &sA[cur][0];
    const uint8_t* bufB = &sB[cur][0];

    // B fragments (persist through the step: 16 regs)
    union opnd { i32x4 h[2]; i32x8 v; };
    opnd ub[2];
#pragma unroll
    for (int j = 0; j < 2; j++) {
      ub[j].h[0] = *(const i32x4*)(bufB + boff[j][0]);
      ub[j].h[1] = *(const i32x4*)(bufB + boff[j][1]);
    }

    // stage tile it+2 (issue now; lands 2 steps later; hides under MFMA)
    if (it + 2 < NT) {
      const i64 kt = (i64)(it + 2) * BKB;
#pragma unroll
      for (int j = 0; j < 4; j++)
        gload_lds16(gA + src[j] + kt, &sA[st2][t * 16 + j * 4096]);
#pragma unroll
      for (int j = 0; j < 2; j++)
        gload_lds16(gB + src[j] + kt, &sB[st2][t * 16 + j * 4096]);
    }

    __builtin_amdgcn_s_setprio(1);
#pragma unroll
    for (int i = 0; i < 4; i++) {
      opnd ua;
      ua.h[0] = *(const i32x4*)(bufA + aoff[i][0]);
      ua.h[1] = *(const i32x4*)(bufA + aoff[i][1]);
#pragma unroll
      for (int j = 0; j < 2; j++)
        acc[i][j] = __builtin_amdgcn_mfma_scale_f32_32x32x64_f8f6f4(
            ua.v, ub[j].v, acc[i][j],
            0, 0,          // cbsz=fp8(e4m3), blgp=fp8(e4m3)
            0, 127,        // scale_a = e8m0 1.0
            0, 127);       // scale_b = e8m0 1.0
    }
    __builtin_amdgcn_s_setprio(0);

    cur = (cur == 2) ? 0 : cur + 1;
    st2 = (st2 == 2) ? 0 : st2 + 1;
  }

  // ---- epilogue: bf16_rne(acc*(sx*sw) + bias) stored as FP32 -------------
  // 32x32 C/D layout (m74/m101): col = lane&31, row = (reg&3)+8*(reg>>2)+4*g
  const float sc = xs[0] * wsc[0];
#pragma unroll
  for (int j = 0; j < 2; j++) {
    const int col = bn * BN + wn + j * 32 + r31;
    const float bv = bias[col];
#pragma unroll
    for (int i = 0; i < 4; i++) {
      const int rowbase = bm * BM + wm + i * 32 + 4 * g;
#pragma unroll
      for (int reg = 0; reg < 16; reg++) {
        const int row = rowbase + (reg & 3) + 8 * (reg >> 2);
        C[(i64)row * N + col] = bf16_rne_f32(acc[i][j][reg] * sc + bv);
      }
    }
  }
}

extern "C" void kernel_launch(void* const* d_in, const int* in_sizes, int n_in,
                              void* d_out, int out_size, void* d_ws, size_t ws_size,
                              hipStream_t stream) {
  // Verified I/O model (R11 oracle + R12-R26 passes): declared order, element
  // counts, ALL buffers fp32-stored bf16-valued, output fp32.
  const float* x = (const float*)d_in[0];
  const float* w = (const float*)d_in[1];
  const float* bias = (const float*)d_in[2];
  const float* x_scale = (const float*)d_in[3];
  const float* w_scale = (const float*)d_in[4];

  const int N = in_sizes[2];
  const int K = in_sizes[1] / N;
  const int M = in_sizes[0] / K;

  uint8_t* xq = (uint8_t*)d_ws;                     // M*K = 32 MB
  uint8_t* wq = (uint8_t*)d_ws + (size_t)M * K;     // N*K = 64 MB

  {
    const int n16 = (M * K) / 16;
    quant_fp8_from_f32<<<(n16 + 255) / 256, 256, 0, stream>>>(x, x_scale, xq, n16);
  }
  {
    const int n16 = (int)(((i64)N * K) / 16);
    quant_fp8_from_f32<<<(n16 + 255) / 256, 256, 0, stream>>>(w, w_scale, wq, n16);
  }

  dim3 grid((M / BM) * (N / BN));
  gemm_fp8_mx<<<grid, 256, 0, stream>>>(
      xq, wq, bias, x_scale, w_scale, (float*)d_out, M, N, K);
}